// Round 5
// baseline (218.850 us; speedup 1.0000x reference)
//
#include <hip/hip_runtime.h>
#include <hip/hip_bf16.h>
#include <hip/hip_fp16.h>

#define EPS 1e-5f
#define NE_ 100000
#define B_  256

typedef _Float16 half4 __attribute__((ext_vector_type(4)));
typedef _Float16 half8 __attribute__((ext_vector_type(8)));
typedef float floatx4 __attribute__((ext_vector_type(4)));
typedef float floatx16 __attribute__((ext_vector_type(16)));

// ws layout (fp32 element offsets):
//   partials : [20][256][100]       @ 0        (512000 floats)
//   h16      : fp16 [14][256][8]    @ 512000   (57 KB)
#define WS_PART  0
#define WS_H16   512000

// =====================================================================
// Kernel 1: fused conv + fc split-K GEMM.
// Channel-aligned K-split: 20 slices x 5 channels (K=180 each) makes the
// fusion redundancy-free. 8 samples/block (640 blocks = 2.5/CU for
// latency hiding). Per-(b,o) summation order identical across versions
// -> bit-identical partials.
// =====================================================================
__global__ __launch_bounds__(256) void k_convfc(
    const float* __restrict__ emb_e,
    const float* __restrict__ emb_rel,
    const float* __restrict__ bnr_g, const float* __restrict__ bnr_b,
    const float* __restrict__ bnr_m, const float* __restrict__ bnr_v,
    const float* __restrict__ bn0_g, const float* __restrict__ bn0_b,
    const float* __restrict__ bn0_m, const float* __restrict__ bn0_v,
    const float* __restrict__ bn1_g, const float* __restrict__ bn1_b,
    const float* __restrict__ bn1_m, const float* __restrict__ bn1_v,
    const float* __restrict__ fc_w,   // [3600][100]
    const int* __restrict__ e1, const int* __restrict__ rel,
    float* __restrict__ partials)     // [20][256][100]
{
    __shared__ float x0s[8][100];     // bn0-normalized entity embeddings
    __shared__ float fss[8][126];     // bn_rel-normalized filter slice (5ch x 25)
    __shared__ float x1s[8][184];     // conv output slice (5ch x 36), bn1+relu

    const int bg = blockIdx.x;        // 32 sample-groups of 8
    const int ks = blockIdx.y;        // 20 channel-chunks of 5
    const int c0 = ks * 5;
    const int b0 = bg * 8;
    const int t  = threadIdx.x;

    const float sc0 = bn0_g[0] * rsqrtf(bn0_v[0] + EPS);
    const float sh0 = bn0_b[0] - bn0_m[0] * sc0;

    // stage x0 (8 samples x 100) with bn0 applied
    for (int idx = t; idx < 8 * 100; idx += 256) {
        int s = idx / 100, j = idx - s * 100;
        x0s[s][j] = emb_e[(size_t)e1[b0 + s] * 100 + j] * sc0 + sh0;
    }
    // stage filter slice (8 samples x 125) with bn_rel applied
    for (int idx = t; idx < 8 * 125; idx += 256) {
        int s = idx / 125, j = idx - s * 125;
        int g = c0 * 25 + j;
        float sc = bnr_g[g] * rsqrtf(bnr_v[g] + EPS);
        fss[s][j] = (emb_rel[(size_t)rel[b0 + s] * 2500 + g] - bnr_m[g]) * sc + bnr_b[g];
    }
    __syncthreads();

    // conv: 8 samples x 5 channels x 36 spatial = 1440 outputs
    for (int idx = t; idx < 8 * 180; idx += 256) {
        int s = idx / 180, r = idx - s * 180;
        int cl = r / 36, p = r - cl * 36;
        int hh = p / 6, ww = p - hh * 6;
        float sum = 0.f;
        #pragma unroll
        for (int ky = 0; ky < 5; ky++) {
            #pragma unroll
            for (int kx = 0; kx < 5; kx++) {
                sum += x0s[s][(hh + ky) * 10 + ww + kx] * fss[s][cl * 25 + ky * 5 + kx];
            }
        }
        int c = c0 + cl;
        float sc = bn1_g[c] * rsqrtf(bn1_v[c] + EPS);
        float y = (sum - bn1_m[c]) * sc + bn1_b[c];
        x1s[s][r] = fmaxf(y, 0.f);
    }
    __syncthreads();

    // split-K GEMM: [8 x 180] x [180 x 100] -> partials[ks]
    const int o  = t & 127;
    const int mg = t >> 7;
    if (o >= 100) return;

    float acc[4] = {0.f, 0.f, 0.f, 0.f};
    const float* wp = fc_w + (size_t)(c0 * 36) * 100 + o;

    for (int k0 = 0; k0 < 180; k0 += 9) {
        float wv[9];
        #pragma unroll
        for (int u = 0; u < 9; u++) wv[u] = wp[(size_t)(k0 + u) * 100];
        #pragma unroll
        for (int u = 0; u < 9; u++) {
            #pragma unroll
            for (int j = 0; j < 4; j++)
                acc[j] += x1s[mg + 2 * j][k0 + u] * wv[u];
        }
    }
    #pragma unroll
    for (int j = 0; j < 4; j++)
        partials[(size_t)ks * 25600 + (size_t)(b0 + mg + 2 * j) * 100 + o] = acc[j];
}

// =====================================================================
// Kernel 2: reduce split-K + fc_b + BN2 + ReLU -> h16 in MFMA-A layout
//   h16[(k>>3)*256*8 + b*8 + (k&7)] = fp16(h[b][k]), k in [0,100); pad [100,112)=0
// =====================================================================
__global__ __launch_bounds__(256) void k_reduce(
    const float* __restrict__ partials,   // [20][256][100]
    const float* __restrict__ fc_b,
    const float* __restrict__ bn2_g, const float* __restrict__ bn2_b,
    const float* __restrict__ bn2_m, const float* __restrict__ bn2_v,
    _Float16* __restrict__ h16)           // [14][256][8]
{
    const int flat = blockIdx.x * 256 + threadIdx.x;   // b*100 + o
    const int b = flat / 100;
    const int o = flat - b * 100;
    float s = fc_b[o];
    #pragma unroll
    for (int ks = 0; ks < 20; ks++) s += partials[(size_t)ks * 25600 + flat];
    float sc = bn2_g[o] * rsqrtf(bn2_v[o] + EPS);
    float y = (s - bn2_m[o]) * sc + bn2_b[o];
    y = fmaxf(y, 0.f);
    h16[((o >> 3) * 256 + b) * 8 + (o & 7)] = (_Float16)y;
    if (o < 12) {   // zero-pad k = 100..111
        int kp = 100 + o;
        h16[((kp >> 3) * 256 + b) * 8 + (kp & 7)] = (_Float16)0.f;
    }
}

// =====================================================================
// Kernel 3: out[b][e] = sigmoid(h[b].emb_e[e] + bias[e]) via f16 MFMA.
// Block = 128 e-cols x all 256 batch rows (8 m-tiles); grid ceil(NE/128).
// WAVE-PRIVATE emb_e staging: wave w only ever reads LDS chunks
// [w*14, w*14+14) (its own 32 rows), so each wave stages its own
// partition and NO __syncthreads is needed (same-wave ds ordering via
// compiler lgkmcnt). Staging uses the row-interleaved lane map
// r = rp*8 + (lane>>3), g = (lane&7) + 8*i  (k = 4g):
//   - no integer division
//   - global reads: 8 x 128B contiguous segments per inst (coalesced),
//     nontemporal (emb_e is read exactly once grid-wide)
//   - LDS writes packed as half4 ds_write_b64; 8 distinct rows per inst
//     spreads banks (~4-way instead of ~12-way same-row conflicts)
// Values go through the identical scalar RNE fp32->fp16 cvt and the
// identical MFMA order -> bit-identical output.
// D layout (32x32): col = lane&31, row = (r&3) + 8*(r>>2) + 4*(lane>>5).
// out stores nontemporal (write-once stream).
// =====================================================================
__global__ __launch_bounds__(256) void k_scores(
    const float* __restrict__ emb_e,
    const float* __restrict__ bias,
    const _Float16* __restrict__ h16,   // [14][256][8]
    float* __restrict__ out)            // [256][NE]
{
    __shared__ _Float16 ebf[4 * 14 * 32 * 8];   // 28 KB, wave-partitioned

    const int t    = threadIdx.x;
    const int wave = t >> 6;
    const int lane = t & 63;
    const int l31  = lane & 31;
    const int hf   = lane >> 5;

    const int n0 = blockIdx.x * 128 + wave * 32;
    const int e  = n0 + l31;

    // ---- wave-private staging: own 32 rows (3200 floats) -> fp16 LDS ----
    {
        const size_t gwave = (size_t)blockIdx.x * 12800 + (size_t)wave * 3200;
        _Float16* wbuf = ebf + wave * 14 * 256;
        const int lr = lane >> 3;          // 0..7
        const int lg = lane & 7;           // 0..7

        #pragma unroll
        for (int rp = 0; rp < 4; rp++) {
            const int r = rp * 8 + lr;     // 0..31
            #pragma unroll
            for (int i = 0; i < 4; i++) {
                const int g = lg + 8 * i;  // k-group, k = 4g
                if (g < 25) {
                    const size_t gf = gwave + (size_t)(r * 100 + g * 4);
                    floatx4 v;
                    if (gf + 4 <= (size_t)NE_ * 100) {   // 10,000,000 % 4 == 0
                        v = __builtin_nontemporal_load((const floatx4*)(emb_e + gf));
                    } else {
                        v = (floatx4){0.f, 0.f, 0.f, 0.f};
                    }
                    half4 h;
                    h[0] = (_Float16)v[0]; h[1] = (_Float16)v[1];
                    h[2] = (_Float16)v[2]; h[3] = (_Float16)v[3];
                    // chunk = g>>1, within-chunk fp16 offset = r*8 + (g&1)*4
                    *(half4*)&wbuf[(g >> 1) * 256 + r * 8 + (g & 1) * 4] = h;
                }
            }
        }
        // zero-pad k = 100,104,108 (g = 25,26,27) for own 32 rows
        half4 z;
        z[0] = (_Float16)0.f; z[1] = (_Float16)0.f;
        z[2] = (_Float16)0.f; z[3] = (_Float16)0.f;
        if (lane < 32) {
            #pragma unroll
            for (int g = 25; g < 28; g++)
                *(half4*)&wbuf[(g >> 1) * 256 + lane * 8 + (g & 1) * 4] = z;
        }
    }
    // no __syncthreads: each wave reads only its own ebf partition.

    // ---- B-frags for 7 k-chunks from LDS (contiguous 16B per lane) ----
    half8 bf[7];
    {
        const half8* eb8 = (const half8*)ebf;       // index = chunk*32 + l31
        #pragma unroll
        for (int kc = 0; kc < 7; kc++)
            bf[kc] = eb8[(wave * 14 + kc * 2 + hf) * 32 + l31];
    }

    const half8* hA = (const half8*)h16;   // index = chunk8*256 + m
    const float bb = (e < NE_) ? bias[e] : 0.f;

    #pragma unroll 2
    for (int mt = 0; mt < 8; mt++) {
        floatx16 acc;
        #pragma unroll
        for (int r = 0; r < 16; r++) acc[r] = 0.f;

        const int m = mt * 32 + l31;
        #pragma unroll
        for (int kc = 0; kc < 7; kc++) {
            const half8 a = hA[(kc * 2 + hf) * 256 + m];
            acc = __builtin_amdgcn_mfma_f32_32x32x16_f16(a, bf[kc], acc, 0, 0, 0);
        }

        if (e < NE_) {
            #pragma unroll
            for (int r = 0; r < 16; r++) {
                const int row = mt * 32 + (r & 3) + 8 * (r >> 2) + 4 * hf;
                const float v = 1.f / (1.f + __expf(-(acc[r] + bb)));
                __builtin_nontemporal_store(v, &out[(size_t)row * NE_ + e]);
            }
        }
    }
}

extern "C" void kernel_launch(void* const* d_in, const int* in_sizes, int n_in,
                              void* d_out, int out_size, void* d_ws, size_t ws_size,
                              hipStream_t stream) {
    const float* emb_e   = (const float*)d_in[0];
    const float* emb_rel = (const float*)d_in[1];
    const float* bnr_g   = (const float*)d_in[2];
    const float* bnr_b   = (const float*)d_in[3];
    const float* bnr_m   = (const float*)d_in[4];
    const float* bnr_v   = (const float*)d_in[5];
    const float* bn0_g   = (const float*)d_in[6];
    const float* bn0_b   = (const float*)d_in[7];
    const float* bn0_m   = (const float*)d_in[8];
    const float* bn0_v   = (const float*)d_in[9];
    const float* bn1_g   = (const float*)d_in[10];
    const float* bn1_b   = (const float*)d_in[11];
    const float* bn1_m   = (const float*)d_in[12];
    const float* bn1_v   = (const float*)d_in[13];
    const float* fc_w    = (const float*)d_in[14];
    const float* fc_b    = (const float*)d_in[15];
    const float* bn2_g   = (const float*)d_in[16];
    const float* bn2_b   = (const float*)d_in[17];
    const float* bn2_m   = (const float*)d_in[18];
    const float* bn2_v   = (const float*)d_in[19];
    const float* bias    = (const float*)d_in[20];
    const int* e1  = (const int*)d_in[21];
    const int* rel = (const int*)d_in[22];

    float* ws       = (float*)d_ws;
    float* partials = ws + WS_PART;
    _Float16* h16   = (_Float16*)(ws + WS_H16);

    k_convfc<<<dim3(32, 20), dim3(256), 0, stream>>>(
        emb_e, emb_rel,
        bnr_g, bnr_b, bnr_m, bnr_v,
        bn0_g, bn0_b, bn0_m, bn0_v,
        bn1_g, bn1_b, bn1_m, bn1_v,
        fc_w, e1, rel, partials);

    k_reduce<<<dim3(100), dim3(256), 0, stream>>>(
        partials, fc_b, bn2_g, bn2_b, bn2_m, bn2_v, h16);

    k_scores<<<dim3((NE_ + 127) / 128), dim3(256), 0, stream>>>(
        emb_e, bias, h16, (float*)d_out);
}